// Round 2
// baseline (36.439 us; speedup 1.0000x reference)
//
#include <hip/hip_runtime.h>

#define NB 32
#define NS 8192
#define ND 64
#define CHUNK 256
#define NCHUNK (NS / CHUNK)   // 32
#define INV_T 0.125f          // 1/8.0
#define PSTRIDE 66            // m, l, acc[64]

// ---------------- Phase 1: per-(batch, S-chunk) partial flash attention ----
// Thread-per-row scores (16 independent float4 K loads, q from LDS broadcast),
// then group-of-16 V accumulation (16 independent float4 V loads, e from LDS).
__global__ __launch_bounds__(256) void attn_p1(
    const float* __restrict__ q, const float* __restrict__ k,
    const float* __restrict__ v, float* __restrict__ attn,
    float* __restrict__ part)
{
    const int blk = blockIdx.x;       // 0 .. NB*NCHUNK-1
    const int b   = blk >> 5;         // / NCHUNK
    const int c   = blk & (NCHUNK - 1);
    const int tid = threadIdx.x;
    const int w   = tid >> 6;         // wave 0..3
    const int l   = tid & 63;         // lane
    const int l16 = l & 15;
    const int g   = l >> 4;

    __shared__ float qlds[ND];
    __shared__ float es[CHUNK];
    __shared__ float redm[4];
    __shared__ float redl[4];
    __shared__ float accl[4][ND];

    if (tid < ND / 4) {
        reinterpret_cast<float4*>(qlds)[tid] =
            reinterpret_cast<const float4*>(q + b * ND)[tid];
    }
    __syncthreads();

    // ---- scores: thread tid owns row c*CHUNK + tid
    const size_t kb  = (size_t)b * NS * ND;
    const int    row = c * CHUNK + tid;
    const float4* krow = reinterpret_cast<const float4*>(k + kb + (size_t)row * ND);

    float4 a = make_float4(0.f, 0.f, 0.f, 0.f);
#pragma unroll
    for (int j = 0; j < 16; ++j) {
        const float4 kv = krow[j];                          // independent loads
        const float4 qv = reinterpret_cast<float4*>(qlds)[j]; // broadcast
        a.x += kv.x * qv.x; a.y += kv.y * qv.y;
        a.z += kv.z * qv.z; a.w += kv.w * qv.w;
    }
    const float s = (a.x + a.y + a.z + a.w) * INV_T;
    attn[(size_t)b * NS + row] = s;   // raw score, coalesced

    // ---- block max
    float m = s;
#pragma unroll
    for (int d = 1; d < 64; d <<= 1) m = fmaxf(m, __shfl_xor(m, d));
    if (l == 0) redm[w] = m;
    __syncthreads();
    const float mc = fmaxf(fmaxf(redm[0], redm[1]), fmaxf(redm[2], redm[3]));

    // ---- exp + chunk l
    const float e = __expf(s - mc);
    es[tid] = e;
    float ls = e;
#pragma unroll
    for (int d = 1; d < 64; d <<= 1) ls += __shfl_xor(ls, d);
    if (l == 0) redl[w] = ls;
    __syncthreads();   // es[] visible to all

    // ---- V accumulation: group (w,g) owns local rows [w*64+g*16, +16), lane
    //      l16 owns dims [l16*4, l16*4+4)
    const int rbase = w * 64 + g * 16;
    float4 acc = make_float4(0.f, 0.f, 0.f, 0.f);
#pragma unroll
    for (int i = 0; i < 16; ++i) {
        const float ei = es[rbase + i];   // broadcast within group
        const float4 vv = reinterpret_cast<const float4*>(
            v + kb + (size_t)(c * CHUNK + rbase + i) * ND)[l16];
        acc.x += ei * vv.x; acc.y += ei * vv.y;
        acc.z += ei * vv.z; acc.w += ei * vv.w;
    }

    // reduce acc across the 4 groups of the wave
    acc.x += __shfl_xor(acc.x, 16); acc.y += __shfl_xor(acc.y, 16);
    acc.z += __shfl_xor(acc.z, 16); acc.w += __shfl_xor(acc.w, 16);
    acc.x += __shfl_xor(acc.x, 32); acc.y += __shfl_xor(acc.y, 32);
    acc.z += __shfl_xor(acc.z, 32); acc.w += __shfl_xor(acc.w, 32);
    if (l < 16) {
        accl[w][l16 * 4 + 0] = acc.x;
        accl[w][l16 * 4 + 1] = acc.y;
        accl[w][l16 * 4 + 2] = acc.z;
        accl[w][l16 * 4 + 3] = acc.w;
    }
    __syncthreads();

    float* pp = part + (size_t)blk * PSTRIDE;
    if (tid == 0) {
        pp[0] = mc;
        pp[1] = redl[0] + redl[1] + redl[2] + redl[3];
    }
    if (tid < ND) {
        pp[2 + tid] = accl[0][tid] + accl[1][tid] + accl[2][tid] + accl[3][tid];
    }
}

// ---------------- Phase 2: reduce chunk partials per batch ---------------
__global__ __launch_bounds__(64) void attn_p2(
    const float* __restrict__ part, float* __restrict__ out,
    float* __restrict__ stats)
{
    const int b = blockIdx.x;
    const int t = threadIdx.x;           // dim 0..63
    const float* pb = part + (size_t)b * NCHUNK * PSTRIDE;

    float m = -1e30f;
    for (int c = 0; c < NCHUNK; ++c) m = fmaxf(m, pb[c * PSTRIDE]);

    float lsum = 0.f, acc = 0.f;
    for (int c = 0; c < NCHUNK; ++c) {
        const float wgt = __expf(pb[c * PSTRIDE] - m);
        lsum += pb[c * PSTRIDE + 1] * wgt;
        acc  += pb[c * PSTRIDE + 2 + t] * wgt;
    }
    const float invl = 1.f / lsum;
    out[b * ND + t] = acc * invl;
    if (t == 0) { stats[b * 2] = m; stats[b * 2 + 1] = invl; }
}

// ---------------- Phase 3: rescale raw scores -> probabilities -----------
__global__ __launch_bounds__(256) void attn_p3(
    float* __restrict__ attn, const float* __restrict__ stats)
{
    const int idx = blockIdx.x * 256 + threadIdx.x;  // over NB*NS/4 float4s
    const int b = idx >> 11;                         // NS/4 = 2048 per batch
    const float m    = stats[b * 2];
    const float invl = stats[b * 2 + 1];
    float4 sv = reinterpret_cast<float4*>(attn)[idx];
    sv.x = __expf(sv.x - m) * invl;
    sv.y = __expf(sv.y - m) * invl;
    sv.z = __expf(sv.z - m) * invl;
    sv.w = __expf(sv.w - m) * invl;
    reinterpret_cast<float4*>(attn)[idx] = sv;
}

extern "C" void kernel_launch(void* const* d_in, const int* in_sizes, int n_in,
                              void* d_out, int out_size, void* d_ws, size_t ws_size,
                              hipStream_t stream)
{
    const float* q = (const float*)d_in[0];   // [32, 64]
    const float* k = (const float*)d_in[1];   // [32, 8192, 64]
    const float* v = (const float*)d_in[2];   // [32, 8192, 64]

    float* out  = (float*)d_out;              // [32,1,64]  -> 2048 floats
    float* attn = out + NB * ND;              // [32,1,8192]-> 262144 floats

    float* part  = (float*)d_ws;                         // [NB*NCHUNK][66]
    float* stats = part + (size_t)NB * NCHUNK * PSTRIDE; // [NB][2]

    attn_p1<<<NB * NCHUNK, 256, 0, stream>>>(q, k, v, attn, part);
    attn_p2<<<NB, 64, 0, stream>>>(part, out, stats);
    attn_p3<<<(NB * NS / 4) / 256, 256, 0, stream>>>(attn, stats);
}